// Round 3
// baseline (543.364 us; speedup 1.0000x reference)
//
#include <hip/hip_runtime.h>
#include <stdint.h>

typedef unsigned long long u64;

// ---------------------------------------------------------------------------
// Binarized GraphSAGE, 2 layers. bin_act rows = sign bits + alpha; bin_linear =
// popcount(x^w). rel-linear pushed through scatter_mean (linearity). Layer1 is
// wave-per-node with register-staged edges + shfl broadcast. binact is
// 8-rows-per-wave (row per 8-lane group) so it is HBM-BW bound, not
// cross-lane-latency bound.
//
// Bit layout for 128-wide rows (x rows AND layer1 weight rows — must match;
// guaranteed by sharing pack_row128):
//   element e = (it*8+c)*4+k  ->  word (c>>2), bit 16*(c&3) + it*4 + k
//   (c = lane&7 column chunk, it = 0..3, k = float4 component)
// Layer2 (n=256): element e -> word (e>>6), bit (e&63)  [natural]
// ---------------------------------------------------------------------------

struct __align__(32) Rec {        // one binarized row: 128 sign bits + alpha
  u64 b0, b1;
  float a;
  float pad0, pad1, pad2;
};

// sign-pack one 128-elem row held by an 8-lane group (16 elems/lane), vs mu.
// Returns the two assembled 64-bit words (valid in every lane of the group).
__device__ __forceinline__ void pack_row128(
    float4 v0, float4 v1, float4 v2, float4 v3, float mu, int c,
    u64& w0, u64& w1)
{
  unsigned m = 0;
  m |= (v0.x > mu) ? 1u << 0  : 0u;
  m |= (v0.y > mu) ? 1u << 1  : 0u;
  m |= (v0.z > mu) ? 1u << 2  : 0u;
  m |= (v0.w > mu) ? 1u << 3  : 0u;
  m |= (v1.x > mu) ? 1u << 4  : 0u;
  m |= (v1.y > mu) ? 1u << 5  : 0u;
  m |= (v1.z > mu) ? 1u << 6  : 0u;
  m |= (v1.w > mu) ? 1u << 7  : 0u;
  m |= (v2.x > mu) ? 1u << 8  : 0u;
  m |= (v2.y > mu) ? 1u << 9  : 0u;
  m |= (v2.z > mu) ? 1u << 10 : 0u;
  m |= (v2.w > mu) ? 1u << 11 : 0u;
  m |= (v3.x > mu) ? 1u << 12 : 0u;
  m |= (v3.y > mu) ? 1u << 13 : 0u;
  m |= (v3.z > mu) ? 1u << 14 : 0u;
  m |= (v3.w > mu) ? 1u << 15 : 0u;
  u64 wv = (u64)m << (16 * (c & 3));
  wv |= __shfl_xor(wv, 1);
  wv |= __shfl_xor(wv, 2);
  u64 other = __shfl_xor(wv, 4);
  w0 = (c & 4) ? other : wv;
  w1 = (c & 4) ? wv : other;
}

// ---- bin_act(x): 8 rows per wave, 16 elems per lane ------------------------
__global__ __launch_bounds__(256) void binact128_kernel(
    const float* __restrict__ x, int nrows, Rec* __restrict__ rec)
{
  int lane = threadIdx.x & 63;
  int wid  = blockIdx.x * 4 + (threadIdx.x >> 6);
  int g = lane >> 3;           // row within wave's 8-row group
  int c = lane & 7;            // column chunk
  int row = wid * 8 + g;
  int rowc = row < nrows ? row : nrows - 1;
  const float4* xr = (const float4*)(x + (size_t)rowc * 128);
  float4 v0 = xr[c];
  float4 v1 = xr[c + 8];
  float4 v2 = xr[c + 16];
  float4 v3 = xr[c + 24];

  float s = (v0.x + v0.y + v0.z + v0.w) + (v1.x + v1.y + v1.z + v1.w)
          + (v2.x + v2.y + v2.z + v2.w) + (v3.x + v3.y + v3.z + v3.w);
  s += __shfl_xor(s, 1); s += __shfl_xor(s, 2); s += __shfl_xor(s, 4);
  float mu = s * (1.0f / 128.0f);

  float ss = 0.f, sa = 0.f;
  {
    float d;
    d = v0.x - mu; ss += d * d; sa += fabsf(d);
    d = v0.y - mu; ss += d * d; sa += fabsf(d);
    d = v0.z - mu; ss += d * d; sa += fabsf(d);
    d = v0.w - mu; ss += d * d; sa += fabsf(d);
    d = v1.x - mu; ss += d * d; sa += fabsf(d);
    d = v1.y - mu; ss += d * d; sa += fabsf(d);
    d = v1.z - mu; ss += d * d; sa += fabsf(d);
    d = v1.w - mu; ss += d * d; sa += fabsf(d);
    d = v2.x - mu; ss += d * d; sa += fabsf(d);
    d = v2.y - mu; ss += d * d; sa += fabsf(d);
    d = v2.z - mu; ss += d * d; sa += fabsf(d);
    d = v2.w - mu; ss += d * d; sa += fabsf(d);
    d = v3.x - mu; ss += d * d; sa += fabsf(d);
    d = v3.y - mu; ss += d * d; sa += fabsf(d);
    d = v3.z - mu; ss += d * d; sa += fabsf(d);
    d = v3.w - mu; ss += d * d; sa += fabsf(d);
  }
  ss += __shfl_xor(ss, 1); ss += __shfl_xor(ss, 2); ss += __shfl_xor(ss, 4);
  sa += __shfl_xor(sa, 1); sa += __shfl_xor(sa, 2); sa += __shfl_xor(sa, 4);
  float sd = sqrtf(ss * (1.0f / 127.0f));            // ddof=1
  float a  = (sa * (1.0f / 128.0f)) / (sd + 1e-4f);

  u64 w0, w1;
  pack_row128(v0, v1, v2, v3, mu, c, w0, w1);
  if (c == 0 && row < nrows) {
    Rec* rp = &rec[row];
    *(ulonglong2*)rp = make_ulonglong2(w0, w1);
    rp->a = a;
  }
}

// ---- weight prep (128-in): identical bit layout via pack_row128 ------------
__global__ __launch_bounds__(256) void prep_w128_kernel(
    const float* __restrict__ w, int nrows,
    ulonglong2* __restrict__ wbits, float* __restrict__ m)
{
  int lane = threadIdx.x & 63;
  int wid  = blockIdx.x * 4 + (threadIdx.x >> 6);
  int g = lane >> 3, c = lane & 7;
  int row = wid * 8 + g;
  int rowc = row < nrows ? row : nrows - 1;
  const float4* wr = (const float4*)(w + (size_t)rowc * 128);
  float4 v0 = wr[c];
  float4 v1 = wr[c + 8];
  float4 v2 = wr[c + 16];
  float4 v3 = wr[c + 24];
  float s = fabsf(v0.x) + fabsf(v0.y) + fabsf(v0.z) + fabsf(v0.w)
          + fabsf(v1.x) + fabsf(v1.y) + fabsf(v1.z) + fabsf(v1.w)
          + fabsf(v2.x) + fabsf(v2.y) + fabsf(v2.z) + fabsf(v2.w)
          + fabsf(v3.x) + fabsf(v3.y) + fabsf(v3.z) + fabsf(v3.w);
  s += __shfl_xor(s, 1); s += __shfl_xor(s, 2); s += __shfl_xor(s, 4);
  u64 w0, w1;
  pack_row128(v0, v1, v2, v3, 0.0f, c, w0, w1);
  if (c == 0 && row < nrows) {
    wbits[row] = make_ulonglong2(w0, w1);
    m[row] = s * (1.0f / 128.0f);
  }
}

__global__ void prep_w256_kernel(const float* __restrict__ w,
    u64* __restrict__ wbits /*4 words per row*/, float* __restrict__ m)
{
  int o = blockIdx.x, lane = threadIdx.x;
  const float* wr = w + (size_t)o * 256;
  float s = 0.0f;
  u64 b[4];
  #pragma unroll
  for (int wd = 0; wd < 4; wd++) {
    float v = wr[wd * 64 + lane];
    s += fabsf(v);
    b[wd] = __ballot(v > 0.0f);
  }
  #pragma unroll
  for (int off = 32; off > 0; off >>= 1) s += __shfl_xor(s, off);
  if (lane == 0) {
    wbits[o * 4 + 0] = b[0]; wbits[o * 4 + 1] = b[1];
    wbits[o * 4 + 2] = b[2]; wbits[o * 4 + 3] = b[3];
    m[o] = s * (1.0f / 256.0f);
  }
}

// ---- CSR build: histogram, exclusive scan, scatter (reordered src) ---------
__global__ void hist_kernel(const int* __restrict__ dst, int E, int* __restrict__ cnt)
{
  int i = blockIdx.x * blockDim.x + threadIdx.x;
  if (i < E) atomicAdd(&cnt[dst[i]], 1);
}

__global__ __launch_bounds__(1024) void exscan_kernel(
    const int* __restrict__ cnt, int* __restrict__ offs,
    int* __restrict__ cursor, int n)
{
  __shared__ int tot[1024];
  int t = threadIdx.x;
  int chunk = (n + 1023) >> 10;
  int b = t * chunk, e = min(b + chunk, n);
  int s = 0;
  for (int i = b; i < e; i++) s += cnt[i];
  tot[t] = s;
  __syncthreads();
  for (int off = 1; off < 1024; off <<= 1) {
    int v = (t >= off) ? tot[t - off] : 0;
    __syncthreads();
    tot[t] += v;
    __syncthreads();
  }
  int run = (t == 0) ? 0 : tot[t - 1];
  for (int i = b; i < e; i++) {
    offs[i] = run; cursor[i] = run; run += cnt[i];
  }
  if (t == 1023) offs[n] = tot[1023];
}

__global__ void scatter_kernel(const int* __restrict__ dst, const int* __restrict__ src,
                               int E, int* __restrict__ cursor, int* __restrict__ srcs)
{
  int i = blockIdx.x * blockDim.x + threadIdx.x;
  if (i < E) { int p = atomicAdd(&cursor[dst[i]], 1); srcs[p] = src[i]; }
}

// ---- layer 1 fused: scatter-mean + both bin_linears + relu + bin_act(h) ----
// one WAVE per dst node (4 waves/block); lane owns features f = j*64+lane
__global__ __launch_bounds__(256) void layer1_kernel(
    const Rec* __restrict__ rec1,
    const int* __restrict__ offs, const int* __restrict__ srcs,
    const ulonglong2* __restrict__ wb_rel, const float* __restrict__ m_rel,
    const float* __restrict__ b_rel,
    const ulonglong2* __restrict__ wb_root, const float* __restrict__ m_root,
    const float* __restrict__ b_root,
    u64* __restrict__ bits2, float* __restrict__ alpha2)
{
  int lane = threadIdx.x & 63;
  int d = blockIdx.x * 4 + (threadIdx.x >> 6);

  ulonglong2 wr[4], wt[4];
  float mr[4], br[4], mt[4], bt[4];
  #pragma unroll
  for (int j = 0; j < 4; j++) {
    int f = j * 64 + lane;
    wr[j] = wb_rel[f];  mr[j] = m_rel[f];  br[j] = b_rel[f];
    wt[j] = wb_root[f]; mt[j] = m_root[f]; bt[j] = b_root[f];
  }

  int s0 = offs[d], s1 = offs[d + 1];
  float acc2[4] = {0.f, 0.f, 0.f, 0.f};   // sum over edges of a * popc
  float suma = 0.f;                       // sum over edges of a

  for (int base = s0; base < s1; base += 64) {
    int nn = min(64, s1 - base);
    u64 rb0 = 0, rb1 = 0; float ra = 0.f;
    if (lane < nn) {
      int sn = srcs[base + lane];
      const Rec* rp = &rec1[sn];
      ulonglong2 bb = *(const ulonglong2*)rp;
      rb0 = bb.x; rb1 = bb.y; ra = rp->a;
    }
    for (int i = 0; i < nn; i++) {
      u64 bx = __shfl(rb0, i, 64);
      u64 by = __shfl(rb1, i, 64);
      float a = __shfl(ra, i, 64);
      suma += a;
      #pragma unroll
      for (int j = 0; j < 4; j++) {
        int pc = __popcll(bx ^ wr[j].x) + __popcll(by ^ wr[j].y);
        acc2[j] += a * (float)pc;
      }
    }
  }

  float invc = (s1 > s0) ? 1.0f / (float)(s1 - s0) : 1.0f;
  const Rec* rd = &rec1[d];               // xt = bin_act(x[:n1]) row d
  u64 xb0 = rd->b0, xb1 = rd->b1;
  float ax = rd->a;

  float z[4];
  #pragma unroll
  for (int j = 0; j < 4; j++) {
    int pcr = __popcll(xb0 ^ wt[j].x) + __popcll(xb1 ^ wt[j].y);
    float rel = mr[j] * (128.0f * suma - 2.0f * acc2[j]) * invc + br[j];
    float rot = mt[j] * ax * (float)(128 - 2 * pcr) + bt[j];
    z[j] = fmaxf(rel + rot, 0.0f);        // relu
  }

  // fused bin_act over this node's 256 z values (all wave-local)
  float s = z[0] + z[1] + z[2] + z[3];
  #pragma unroll
  for (int off = 32; off > 0; off >>= 1) s += __shfl_xor(s, off);
  float mu = s * (1.0f / 256.0f);
  float ss = 0.f, sa = 0.f;
  #pragma unroll
  for (int j = 0; j < 4; j++) {
    float dv = z[j] - mu;
    ss += dv * dv; sa += fabsf(dv);
  }
  #pragma unroll
  for (int off = 32; off > 0; off >>= 1) {
    ss += __shfl_xor(ss, off);
    sa += __shfl_xor(sa, off);
  }
  float sd = sqrtf(ss * (1.0f / 255.0f));  // ddof=1
  float a2 = (sa * (1.0f / 256.0f)) / (sd + 1e-4f);
  u64 wd0 = __ballot(z[0] > mu);           // word j bit l = feature j*64+l
  u64 wd1 = __ballot(z[1] > mu);
  u64 wd2 = __ballot(z[2] > mu);
  u64 wd3 = __ballot(z[3] > mu);
  if (lane == 0) {
    ulonglong2* bp = (ulonglong2*)(bits2 + (size_t)d * 4);
    bp[0] = make_ulonglong2(wd0, wd1);
    bp[1] = make_ulonglong2(wd2, wd3);
    alpha2[d] = a2;
  }
}

// ---- layer 2 fused: scatter-mean + bin_linears + log_softmax ---------------
// one wave per dst node; lane o computes output class o (OUT=64)
__global__ __launch_bounds__(64) void layer2_kernel(
    const u64* __restrict__ bits2, const float* __restrict__ alpha2,
    const int* __restrict__ offs, const int* __restrict__ srcs,
    const u64* __restrict__ wb_rel, const float* __restrict__ m_rel,
    const float* __restrict__ b_rel,
    const u64* __restrict__ wb_root, const float* __restrict__ m_root,
    const float* __restrict__ b_root,
    float* __restrict__ out)
{
  int d = blockIdx.x, o = threadIdx.x;
  u64 w0 = wb_rel[o * 4 + 0], w1 = wb_rel[o * 4 + 1];
  u64 w2 = wb_rel[o * 4 + 2], w3 = wb_rel[o * 4 + 3];
  int s0 = offs[d], s1 = offs[d + 1];
  float acc = 0.0f;
  for (int base = s0; base < s1; base += 64) {
    int nn = min(64, s1 - base);
    u64 rb0 = 0, rb1 = 0, rb2 = 0, rb3 = 0; float ra = 0.f;
    if (o < nn) {
      int sn = srcs[base + o];
      const u64* bp = bits2 + (size_t)sn * 4;
      rb0 = bp[0]; rb1 = bp[1]; rb2 = bp[2]; rb3 = bp[3];
      ra = alpha2[sn];
    }
    for (int i = 0; i < nn; i++) {
      u64 bx0 = __shfl(rb0, i, 64);
      u64 bx1 = __shfl(rb1, i, 64);
      u64 bx2 = __shfl(rb2, i, 64);
      u64 bx3 = __shfl(rb3, i, 64);
      float a = __shfl(ra, i, 64);
      int pc = __popcll(bx0 ^ w0) + __popcll(bx1 ^ w1)
             + __popcll(bx2 ^ w2) + __popcll(bx3 ^ w3);
      acc += a * (float)(256 - 2 * pc);
    }
  }
  int cnt = s1 - s0;
  float invc = 1.0f / (float)(cnt > 0 ? cnt : 1);
  const u64* xp = bits2 + (size_t)d * 4;   // xt2 = bin_act(h[:n2]) row d
  float ax = alpha2[d];
  int pcr = __popcll(xp[0] ^ wb_root[o * 4 + 0]) + __popcll(xp[1] ^ wb_root[o * 4 + 1])
          + __popcll(xp[2] ^ wb_root[o * 4 + 2]) + __popcll(xp[3] ^ wb_root[o * 4 + 3]);
  float z = m_rel[o] * acc * invc + b_rel[o]
          + m_root[o] * ax * (float)(256 - 2 * pcr) + b_root[o];
  // log_softmax over the 64 classes (one wave)
  float mx = z;
  #pragma unroll
  for (int off = 32; off > 0; off >>= 1) mx = fmaxf(mx, __shfl_xor(mx, off));
  float ex = expf(z - mx);
  float se = ex;
  #pragma unroll
  for (int off = 32; off > 0; off >>= 1) se += __shfl_xor(se, off);
  out[(size_t)d * 64 + o] = z - mx - logf(se);
}

// ---------------------------------------------------------------------------
extern "C" void kernel_launch(void* const* d_in, const int* in_sizes, int n_in,
                              void* d_out, int out_size, void* d_ws, size_t ws_size,
                              hipStream_t stream)
{
  const float* x       = (const float*)d_in[0];
  const int*   src1    = (const int*)d_in[1];
  const int*   dst1    = (const int*)d_in[2];
  const int*   src2    = (const int*)d_in[3];
  const int*   dst2    = (const int*)d_in[4];
  const float* w_rel1  = (const float*)d_in[5];
  const float* b_rel1  = (const float*)d_in[6];
  const float* w_root1 = (const float*)d_in[7];
  const float* b_root1 = (const float*)d_in[8];
  const float* w_rel2  = (const float*)d_in[9];
  const float* b_rel2  = (const float*)d_in[10];
  const float* w_root2 = (const float*)d_in[11];
  const float* b_root2 = (const float*)d_in[12];

  const int IN  = 128;
  const int HID = in_sizes[6];            // 256
  const int OUT = in_sizes[10];           // 64
  const int N0  = in_sizes[0] / IN;       // 512000
  const int E1  = in_sizes[1];            // 512000
  const int E2  = in_sizes[3];            // 20480
  const int N1  = 20480;                  // n1 (fixed shape for this problem)
  const int N2  = out_size / OUT;         // 2048
  (void)n_in; (void)ws_size;

  char* p = (char*)d_ws;
  auto alloc = [&](size_t bytes) {
    char* r = p;
    p += (bytes + 255) & ~(size_t)255;
    return r;
  };
  Rec*   rec1   = (Rec*)alloc((size_t)N0 * sizeof(Rec));   // 16.4 MB
  u64*   bits2  = (u64*)alloc((size_t)N1 * 32);
  float* alpha2 = (float*)alloc((size_t)N1 * 4);
  int*   srcs1  = (int*)alloc((size_t)E1 * 4);
  int*   srcs2  = (int*)alloc((size_t)E2 * 4);
  int*   cnt1   = (int*)alloc((size_t)(N1 + N2) * 4);
  int*   cnt2   = cnt1 + N1;
  int*   offs1  = (int*)alloc((size_t)(N1 + 1) * 4);
  int*   offs2  = (int*)alloc((size_t)(N2 + 1) * 4);
  int*   cur1   = (int*)alloc((size_t)N1 * 4);
  int*   cur2   = (int*)alloc((size_t)N2 * 4);
  ulonglong2* wbr1 = (ulonglong2*)alloc((size_t)HID * 16);
  ulonglong2* wbt1 = (ulonglong2*)alloc((size_t)HID * 16);
  u64*   wbr2   = (u64*)alloc((size_t)OUT * 32);
  u64*   wbt2   = (u64*)alloc((size_t)OUT * 32);
  float* m_r1   = (float*)alloc((size_t)HID * 4);
  float* m_t1   = (float*)alloc((size_t)HID * 4);
  float* m_r2   = (float*)alloc((size_t)OUT * 4);
  float* m_t2   = (float*)alloc((size_t)OUT * 4);

  hipMemsetAsync(cnt1, 0, (size_t)(N1 + N2) * 4, stream);

  prep_w128_kernel<<<(HID / 8 + 3) / 4, 256, 0, stream>>>(w_rel1, HID, wbr1, m_r1);
  prep_w128_kernel<<<(HID / 8 + 3) / 4, 256, 0, stream>>>(w_root1, HID, wbt1, m_t1);
  prep_w256_kernel<<<OUT, 64, 0, stream>>>(w_rel2, wbr2, m_r2);
  prep_w256_kernel<<<OUT, 64, 0, stream>>>(w_root2, wbt2, m_t2);

  {
    int waves  = (N0 + 7) / 8;     // 8 rows per wave
    int blocks = (waves + 3) / 4;  // 4 waves per block
    binact128_kernel<<<blocks, 256, 0, stream>>>(x, N0, rec1);
  }

  hist_kernel<<<(E1 + 255) / 256, 256, 0, stream>>>(dst1, E1, cnt1);
  exscan_kernel<<<1, 1024, 0, stream>>>(cnt1, offs1, cur1, N1);
  scatter_kernel<<<(E1 + 255) / 256, 256, 0, stream>>>(dst1, src1, E1, cur1, srcs1);
  layer1_kernel<<<N1 / 4, 256, 0, stream>>>(rec1, offs1, srcs1,
                                            wbr1, m_r1, b_rel1, wbt1, m_t1, b_root1,
                                            bits2, alpha2);

  hist_kernel<<<(E2 + 255) / 256, 256, 0, stream>>>(dst2, E2, cnt2);
  exscan_kernel<<<1, 1024, 0, stream>>>(cnt2, offs2, cur2, N2);
  scatter_kernel<<<(E2 + 255) / 256, 256, 0, stream>>>(dst2, src2, E2, cur2, srcs2);
  layer2_kernel<<<N2, 64, 0, stream>>>(bits2, alpha2, offs2, srcs2,
                                       wbr2, m_r2, b_rel2, wbt2, m_t2, b_root2,
                                       (float*)d_out);
}

// Round 4
// 519.583 us; speedup vs baseline: 1.0458x; 1.0458x over previous
//
#include <hip/hip_runtime.h>
#include <stdint.h>

typedef unsigned long long u64;

// ---------------------------------------------------------------------------
// Binarized GraphSAGE, 2 layers. bin_act rows = sign bits + alpha; bin_linear =
// popcount(x^w). rel-linear pushed through scatter_mean (linearity). Layer1 is
// wave-per-node with register-staged edges + shfl broadcast. binact is
// 8-rows-per-wave (BW-bound). This round: 14 launches -> 7 (merged preps,
// merged hist/scan/scatter across both graphs, memset folded into prep).
//
// Bit layout for 128-wide rows (x rows AND layer1 weight rows — must match;
// guaranteed by sharing pack_row128):
//   element e = (it*8+c)*4+k  ->  word (c>>2), bit 16*(c&3) + it*4 + k
// Layer2 (n=256): element e -> word (e>>6), bit (e&63)  [natural]
// ---------------------------------------------------------------------------

struct __align__(32) Rec {        // one binarized row: 128 sign bits + alpha
  u64 b0, b1;
  float a;
  float pad0, pad1, pad2;
};

// sign-pack one 128-elem row held by an 8-lane group (16 elems/lane), vs mu.
__device__ __forceinline__ void pack_row128(
    float4 v0, float4 v1, float4 v2, float4 v3, float mu, int c,
    u64& w0, u64& w1)
{
  unsigned m = 0;
  m |= (v0.x > mu) ? 1u << 0  : 0u;
  m |= (v0.y > mu) ? 1u << 1  : 0u;
  m |= (v0.z > mu) ? 1u << 2  : 0u;
  m |= (v0.w > mu) ? 1u << 3  : 0u;
  m |= (v1.x > mu) ? 1u << 4  : 0u;
  m |= (v1.y > mu) ? 1u << 5  : 0u;
  m |= (v1.z > mu) ? 1u << 6  : 0u;
  m |= (v1.w > mu) ? 1u << 7  : 0u;
  m |= (v2.x > mu) ? 1u << 8  : 0u;
  m |= (v2.y > mu) ? 1u << 9  : 0u;
  m |= (v2.z > mu) ? 1u << 10 : 0u;
  m |= (v2.w > mu) ? 1u << 11 : 0u;
  m |= (v3.x > mu) ? 1u << 12 : 0u;
  m |= (v3.y > mu) ? 1u << 13 : 0u;
  m |= (v3.z > mu) ? 1u << 14 : 0u;
  m |= (v3.w > mu) ? 1u << 15 : 0u;
  u64 wv = (u64)m << (16 * (c & 3));
  wv |= __shfl_xor(wv, 1);
  wv |= __shfl_xor(wv, 2);
  u64 other = __shfl_xor(wv, 4);
  w0 = (c & 4) ? other : wv;
  w1 = (c & 4) ? wv : other;
}

// pack a 128-wide weight block of rows (8 rows per wave), same layout
__device__ __forceinline__ void prep_w128_block(
    const float* __restrict__ w, int rowbase, int tid,
    ulonglong2* __restrict__ wbits, float* __restrict__ m)
{
  int lane = tid & 63;
  int g = lane >> 3, c = lane & 7;
  int row = rowbase + (tid >> 6) * 8 + g;
  const float4* wr = (const float4*)(w + (size_t)row * 128);
  float4 v0 = wr[c];
  float4 v1 = wr[c + 8];
  float4 v2 = wr[c + 16];
  float4 v3 = wr[c + 24];
  float s = fabsf(v0.x) + fabsf(v0.y) + fabsf(v0.z) + fabsf(v0.w)
          + fabsf(v1.x) + fabsf(v1.y) + fabsf(v1.z) + fabsf(v1.w)
          + fabsf(v2.x) + fabsf(v2.y) + fabsf(v2.z) + fabsf(v2.w)
          + fabsf(v3.x) + fabsf(v3.y) + fabsf(v3.z) + fabsf(v3.w);
  s += __shfl_xor(s, 1); s += __shfl_xor(s, 2); s += __shfl_xor(s, 4);
  u64 w0, w1;
  pack_row128(v0, v1, v2, v3, 0.0f, c, w0, w1);
  if (c == 0) {
    wbits[row] = make_ulonglong2(w0, w1);
    m[row] = s * (1.0f / 128.0f);
  }
}

// pack a 256-wide weight block (1 row per wave, 4 rows per 256-thr block)
__device__ __forceinline__ void prep_w256_block(
    const float* __restrict__ w, int rowbase, int tid,
    u64* __restrict__ wbits, float* __restrict__ m)
{
  int lane = tid & 63;
  int o = rowbase + (tid >> 6);
  const float* wr = w + (size_t)o * 256;
  float s = 0.0f;
  u64 b[4];
  #pragma unroll
  for (int wd = 0; wd < 4; wd++) {
    float v = wr[wd * 64 + lane];
    s += fabsf(v);
    b[wd] = __ballot(v > 0.0f);
  }
  #pragma unroll
  for (int off = 32; off > 0; off >>= 1) s += __shfl_xor(s, off);
  if (lane == 0) {
    wbits[o * 4 + 0] = b[0]; wbits[o * 4 + 1] = b[1];
    wbits[o * 4 + 2] = b[2]; wbits[o * 4 + 3] = b[3];
    m[o] = s * (1.0f / 256.0f);
  }
}

// ---- merged prep: all 4 weight packs + zero the histogram counters ---------
// blocks 0..7: w_rel1 | 8..15: w_root1 | 16..31: w_rel2 | 32..47: w_root2 |
// 48..58: zero cnt (22528 ints)
__global__ __launch_bounds__(256) void prep_all_kernel(
    const float* __restrict__ w_rel1, const float* __restrict__ w_root1,
    const float* __restrict__ w_rel2, const float* __restrict__ w_root2,
    ulonglong2* __restrict__ wbr1, float* __restrict__ m_r1,
    ulonglong2* __restrict__ wbt1, float* __restrict__ m_t1,
    u64* __restrict__ wbr2, float* __restrict__ m_r2,
    u64* __restrict__ wbt2, float* __restrict__ m_t2,
    int* __restrict__ cnt, int cntn)
{
  int b = blockIdx.x, t = threadIdx.x;
  if (b < 8) {
    prep_w128_block(w_rel1, b * 32, t, wbr1, m_r1);
  } else if (b < 16) {
    prep_w128_block(w_root1, (b - 8) * 32, t, wbt1, m_t1);
  } else if (b < 32) {
    prep_w256_block(w_rel2, (b - 16) * 4, t, wbr2, m_r2);
  } else if (b < 48) {
    prep_w256_block(w_root2, (b - 32) * 4, t, wbt2, m_t2);
  } else {
    int base = (b - 48) * 2048 + t * 8;
    #pragma unroll
    for (int k = 0; k < 8; k++) {
      int i = base + k;
      if (i < cntn) cnt[i] = 0;
    }
  }
}

// ---- bin_act(x): 8 rows per wave, 16 elems per lane ------------------------
__global__ __launch_bounds__(256) void binact128_kernel(
    const float* __restrict__ x, int nrows, Rec* __restrict__ rec)
{
  int lane = threadIdx.x & 63;
  int wid  = blockIdx.x * 4 + (threadIdx.x >> 6);
  int g = lane >> 3;           // row within wave's 8-row group
  int c = lane & 7;            // column chunk
  int row = wid * 8 + g;       // grid sized exactly: row < nrows always
  const float4* xr = (const float4*)(x + (size_t)row * 128);
  float4 v0 = xr[c];
  float4 v1 = xr[c + 8];
  float4 v2 = xr[c + 16];
  float4 v3 = xr[c + 24];

  float s = (v0.x + v0.y + v0.z + v0.w) + (v1.x + v1.y + v1.z + v1.w)
          + (v2.x + v2.y + v2.z + v2.w) + (v3.x + v3.y + v3.z + v3.w);
  s += __shfl_xor(s, 1); s += __shfl_xor(s, 2); s += __shfl_xor(s, 4);
  float mu = s * (1.0f / 128.0f);

  float ss = 0.f, sa = 0.f;
  {
    float d;
    d = v0.x - mu; ss += d * d; sa += fabsf(d);
    d = v0.y - mu; ss += d * d; sa += fabsf(d);
    d = v0.z - mu; ss += d * d; sa += fabsf(d);
    d = v0.w - mu; ss += d * d; sa += fabsf(d);
    d = v1.x - mu; ss += d * d; sa += fabsf(d);
    d = v1.y - mu; ss += d * d; sa += fabsf(d);
    d = v1.z - mu; ss += d * d; sa += fabsf(d);
    d = v1.w - mu; ss += d * d; sa += fabsf(d);
    d = v2.x - mu; ss += d * d; sa += fabsf(d);
    d = v2.y - mu; ss += d * d; sa += fabsf(d);
    d = v2.z - mu; ss += d * d; sa += fabsf(d);
    d = v2.w - mu; ss += d * d; sa += fabsf(d);
    d = v3.x - mu; ss += d * d; sa += fabsf(d);
    d = v3.y - mu; ss += d * d; sa += fabsf(d);
    d = v3.z - mu; ss += d * d; sa += fabsf(d);
    d = v3.w - mu; ss += d * d; sa += fabsf(d);
  }
  ss += __shfl_xor(ss, 1); ss += __shfl_xor(ss, 2); ss += __shfl_xor(ss, 4);
  sa += __shfl_xor(sa, 1); sa += __shfl_xor(sa, 2); sa += __shfl_xor(sa, 4);
  float sd = sqrtf(ss * (1.0f / 127.0f));            // ddof=1
  float a  = (sa * (1.0f / 128.0f)) / (sd + 1e-4f);

  u64 w0, w1;
  pack_row128(v0, v1, v2, v3, mu, c, w0, w1);
  if (c == 0) {
    Rec* rp = &rec[row];
    *(ulonglong2*)rp = make_ulonglong2(w0, w1);
    rp->a = a;
  }
}

// ---- CSR build over BOTH graphs: histogram, 2-block scan, scatter ----------
__global__ void hist_all_kernel(
    const int* __restrict__ dst1, int E1, int* __restrict__ cnt1,
    const int* __restrict__ dst2, int E2, int* __restrict__ cnt2)
{
  int i = blockIdx.x * blockDim.x + threadIdx.x;
  if (i < E1) atomicAdd(&cnt1[dst1[i]], 1);
  else if (i < E1 + E2) atomicAdd(&cnt2[dst2[i - E1]], 1);
}

__global__ __launch_bounds__(1024) void exscan2_kernel(
    const int* __restrict__ cnt1, int* __restrict__ offs1, int* __restrict__ cur1, int n1,
    const int* __restrict__ cnt2, int* __restrict__ offs2, int* __restrict__ cur2, int n2)
{
  const int* cnt = blockIdx.x ? cnt2 : cnt1;
  int* offs = blockIdx.x ? offs2 : offs1;
  int* cursor = blockIdx.x ? cur2 : cur1;
  int n = blockIdx.x ? n2 : n1;
  __shared__ int tot[1024];
  int t = threadIdx.x;
  int chunk = (n + 1023) >> 10;
  int b = t * chunk, e = min(b + chunk, n);
  int s = 0;
  for (int i = b; i < e; i++) s += cnt[i];
  tot[t] = s;
  __syncthreads();
  for (int off = 1; off < 1024; off <<= 1) {
    int v = (t >= off) ? tot[t - off] : 0;
    __syncthreads();
    tot[t] += v;
    __syncthreads();
  }
  int run = (t == 0) ? 0 : tot[t - 1];
  for (int i = b; i < e; i++) {
    offs[i] = run; cursor[i] = run; run += cnt[i];
  }
  if (t == 1023) offs[n] = tot[1023];
}

__global__ void scatter_all_kernel(
    const int* __restrict__ dst1, const int* __restrict__ src1, int E1,
    int* __restrict__ cur1, int* __restrict__ srcs1,
    const int* __restrict__ dst2, const int* __restrict__ src2, int E2,
    int* __restrict__ cur2, int* __restrict__ srcs2)
{
  int i = blockIdx.x * blockDim.x + threadIdx.x;
  if (i < E1) {
    int p = atomicAdd(&cur1[dst1[i]], 1); srcs1[p] = src1[i];
  } else if (i < E1 + E2) {
    int j = i - E1;
    int p = atomicAdd(&cur2[dst2[j]], 1); srcs2[p] = src2[j];
  }
}

// ---- layer 1 fused: scatter-mean + both bin_linears + relu + bin_act(h) ----
// one WAVE per dst node (4 waves/block); lane owns features f = j*64+lane
__global__ __launch_bounds__(256) void layer1_kernel(
    const Rec* __restrict__ rec1,
    const int* __restrict__ offs, const int* __restrict__ srcs,
    const ulonglong2* __restrict__ wb_rel, const float* __restrict__ m_rel,
    const float* __restrict__ b_rel,
    const ulonglong2* __restrict__ wb_root, const float* __restrict__ m_root,
    const float* __restrict__ b_root,
    u64* __restrict__ bits2, float* __restrict__ alpha2)
{
  int lane = threadIdx.x & 63;
  int d = blockIdx.x * 4 + (threadIdx.x >> 6);

  ulonglong2 wr[4], wt[4];
  float mr[4], br[4], mt[4], bt[4];
  #pragma unroll
  for (int j = 0; j < 4; j++) {
    int f = j * 64 + lane;
    wr[j] = wb_rel[f];  mr[j] = m_rel[f];  br[j] = b_rel[f];
    wt[j] = wb_root[f]; mt[j] = m_root[f]; bt[j] = b_root[f];
  }

  int s0 = offs[d], s1 = offs[d + 1];
  float acc2[4] = {0.f, 0.f, 0.f, 0.f};   // sum over edges of a * popc
  float suma = 0.f;                       // sum over edges of a

  for (int base = s0; base < s1; base += 64) {
    int nn = min(64, s1 - base);
    u64 rb0 = 0, rb1 = 0; float ra = 0.f;
    if (lane < nn) {
      int sn = srcs[base + lane];
      const Rec* rp = &rec1[sn];
      ulonglong2 bb = *(const ulonglong2*)rp;
      rb0 = bb.x; rb1 = bb.y; ra = rp->a;
    }
    for (int i = 0; i < nn; i++) {
      u64 bx = __shfl(rb0, i, 64);
      u64 by = __shfl(rb1, i, 64);
      float a = __shfl(ra, i, 64);
      suma += a;
      #pragma unroll
      for (int j = 0; j < 4; j++) {
        int pc = __popcll(bx ^ wr[j].x) + __popcll(by ^ wr[j].y);
        acc2[j] += a * (float)pc;
      }
    }
  }

  float invc = (s1 > s0) ? 1.0f / (float)(s1 - s0) : 1.0f;
  const Rec* rd = &rec1[d];               // xt = bin_act(x[:n1]) row d
  u64 xb0 = rd->b0, xb1 = rd->b1;
  float ax = rd->a;

  float z[4];
  #pragma unroll
  for (int j = 0; j < 4; j++) {
    int pcr = __popcll(xb0 ^ wt[j].x) + __popcll(xb1 ^ wt[j].y);
    float rel = mr[j] * (128.0f * suma - 2.0f * acc2[j]) * invc + br[j];
    float rot = mt[j] * ax * (float)(128 - 2 * pcr) + bt[j];
    z[j] = fmaxf(rel + rot, 0.0f);        // relu
  }

  // fused bin_act over this node's 256 z values (all wave-local)
  float s = z[0] + z[1] + z[2] + z[3];
  #pragma unroll
  for (int off = 32; off > 0; off >>= 1) s += __shfl_xor(s, off);
  float mu = s * (1.0f / 256.0f);
  float ss = 0.f, sa = 0.f;
  #pragma unroll
  for (int j = 0; j < 4; j++) {
    float dv = z[j] - mu;
    ss += dv * dv; sa += fabsf(dv);
  }
  #pragma unroll
  for (int off = 32; off > 0; off >>= 1) {
    ss += __shfl_xor(ss, off);
    sa += __shfl_xor(sa, off);
  }
  float sd = sqrtf(ss * (1.0f / 255.0f));  // ddof=1
  float a2 = (sa * (1.0f / 256.0f)) / (sd + 1e-4f);
  u64 wd0 = __ballot(z[0] > mu);           // word j bit l = feature j*64+l
  u64 wd1 = __ballot(z[1] > mu);
  u64 wd2 = __ballot(z[2] > mu);
  u64 wd3 = __ballot(z[3] > mu);
  if (lane == 0) {
    ulonglong2* bp = (ulonglong2*)(bits2 + (size_t)d * 4);
    bp[0] = make_ulonglong2(wd0, wd1);
    bp[1] = make_ulonglong2(wd2, wd3);
    alpha2[d] = a2;
  }
}

// ---- layer 2 fused: scatter-mean + bin_linears + log_softmax ---------------
// one wave per dst node, 4 waves/block; lane o computes output class o (OUT=64)
__global__ __launch_bounds__(256) void layer2_kernel(
    const u64* __restrict__ bits2, const float* __restrict__ alpha2,
    const int* __restrict__ offs, const int* __restrict__ srcs,
    const u64* __restrict__ wb_rel, const float* __restrict__ m_rel,
    const float* __restrict__ b_rel,
    const u64* __restrict__ wb_root, const float* __restrict__ m_root,
    const float* __restrict__ b_root,
    float* __restrict__ out)
{
  int d = blockIdx.x * 4 + (threadIdx.x >> 6);
  int o = threadIdx.x & 63;
  u64 w0 = wb_rel[o * 4 + 0], w1 = wb_rel[o * 4 + 1];
  u64 w2 = wb_rel[o * 4 + 2], w3 = wb_rel[o * 4 + 3];
  int s0 = offs[d], s1 = offs[d + 1];
  float acc = 0.0f;
  for (int base = s0; base < s1; base += 64) {
    int nn = min(64, s1 - base);
    u64 rb0 = 0, rb1 = 0, rb2 = 0, rb3 = 0; float ra = 0.f;
    if (o < nn) {
      int sn = srcs[base + o];
      const u64* bp = bits2 + (size_t)sn * 4;
      rb0 = bp[0]; rb1 = bp[1]; rb2 = bp[2]; rb3 = bp[3];
      ra = alpha2[sn];
    }
    for (int i = 0; i < nn; i++) {
      u64 bx0 = __shfl(rb0, i, 64);
      u64 bx1 = __shfl(rb1, i, 64);
      u64 bx2 = __shfl(rb2, i, 64);
      u64 bx3 = __shfl(rb3, i, 64);
      float a = __shfl(ra, i, 64);
      int pc = __popcll(bx0 ^ w0) + __popcll(bx1 ^ w1)
             + __popcll(bx2 ^ w2) + __popcll(bx3 ^ w3);
      acc += a * (float)(256 - 2 * pc);
    }
  }
  int cnt = s1 - s0;
  float invc = 1.0f / (float)(cnt > 0 ? cnt : 1);
  const u64* xp = bits2 + (size_t)d * 4;   // xt2 = bin_act(h[:n2]) row d
  float ax = alpha2[d];
  int pcr = __popcll(xp[0] ^ wb_root[o * 4 + 0]) + __popcll(xp[1] ^ wb_root[o * 4 + 1])
          + __popcll(xp[2] ^ wb_root[o * 4 + 2]) + __popcll(xp[3] ^ wb_root[o * 4 + 3]);
  float z = m_rel[o] * acc * invc + b_rel[o]
          + m_root[o] * ax * (float)(256 - 2 * pcr) + b_root[o];
  // log_softmax over the 64 classes (one wave)
  float mx = z;
  #pragma unroll
  for (int off = 32; off > 0; off >>= 1) mx = fmaxf(mx, __shfl_xor(mx, off));
  float ex = expf(z - mx);
  float se = ex;
  #pragma unroll
  for (int off = 32; off > 0; off >>= 1) se += __shfl_xor(se, off);
  out[(size_t)d * 64 + o] = z - mx - logf(se);
}

// ---------------------------------------------------------------------------
extern "C" void kernel_launch(void* const* d_in, const int* in_sizes, int n_in,
                              void* d_out, int out_size, void* d_ws, size_t ws_size,
                              hipStream_t stream)
{
  const float* x       = (const float*)d_in[0];
  const int*   src1    = (const int*)d_in[1];
  const int*   dst1    = (const int*)d_in[2];
  const int*   src2    = (const int*)d_in[3];
  const int*   dst2    = (const int*)d_in[4];
  const float* w_rel1  = (const float*)d_in[5];
  const float* b_rel1  = (const float*)d_in[6];
  const float* w_root1 = (const float*)d_in[7];
  const float* b_root1 = (const float*)d_in[8];
  const float* w_rel2  = (const float*)d_in[9];
  const float* b_rel2  = (const float*)d_in[10];
  const float* w_root2 = (const float*)d_in[11];
  const float* b_root2 = (const float*)d_in[12];

  const int IN  = 128;
  const int HID = in_sizes[6];            // 256
  const int OUT = in_sizes[10];           // 64
  const int N0  = in_sizes[0] / IN;       // 512000
  const int E1  = in_sizes[1];            // 512000
  const int E2  = in_sizes[3];            // 20480
  const int N1  = 20480;                  // n1 (fixed shape for this problem)
  const int N2  = out_size / OUT;         // 2048
  (void)n_in; (void)ws_size;

  char* p = (char*)d_ws;
  auto alloc = [&](size_t bytes) {
    char* r = p;
    p += (bytes + 255) & ~(size_t)255;
    return r;
  };
  Rec*   rec1   = (Rec*)alloc((size_t)N0 * sizeof(Rec));   // 16.4 MB
  u64*   bits2  = (u64*)alloc((size_t)N1 * 32);
  float* alpha2 = (float*)alloc((size_t)N1 * 4);
  int*   srcs1  = (int*)alloc((size_t)E1 * 4);
  int*   srcs2  = (int*)alloc((size_t)E2 * 4);
  int*   cnt1   = (int*)alloc((size_t)(N1 + N2) * 4);
  int*   cnt2   = cnt1 + N1;
  int*   offs1  = (int*)alloc((size_t)(N1 + 1) * 4);
  int*   offs2  = (int*)alloc((size_t)(N2 + 1) * 4);
  int*   cur1   = (int*)alloc((size_t)N1 * 4);
  int*   cur2   = (int*)alloc((size_t)N2 * 4);
  ulonglong2* wbr1 = (ulonglong2*)alloc((size_t)HID * 16);
  ulonglong2* wbt1 = (ulonglong2*)alloc((size_t)HID * 16);
  u64*   wbr2   = (u64*)alloc((size_t)OUT * 32);
  u64*   wbt2   = (u64*)alloc((size_t)OUT * 32);
  float* m_r1   = (float*)alloc((size_t)HID * 4);
  float* m_t1   = (float*)alloc((size_t)HID * 4);
  float* m_r2   = (float*)alloc((size_t)OUT * 4);
  float* m_t2   = (float*)alloc((size_t)OUT * 4);

  // 1) all weight preps + zero counters (59 blocks)
  prep_all_kernel<<<59, 256, 0, stream>>>(
      w_rel1, w_root1, w_rel2, w_root2,
      wbr1, m_r1, wbt1, m_t1, wbr2, m_r2, wbt2, m_t2,
      cnt1, N1 + N2);

  // 2) binarize x (exact grid: N0 % 32 rows per block == 0)
  binact128_kernel<<<N0 / 32, 256, 0, stream>>>(x, N0, rec1);

  // 3-5) CSR build for both graphs
  hist_all_kernel<<<(E1 + E2 + 255) / 256, 256, 0, stream>>>(
      dst1, E1, cnt1, dst2, E2, cnt2);
  exscan2_kernel<<<2, 1024, 0, stream>>>(cnt1, offs1, cur1, N1,
                                         cnt2, offs2, cur2, N2);
  scatter_all_kernel<<<(E1 + E2 + 255) / 256, 256, 0, stream>>>(
      dst1, src1, E1, cur1, srcs1, dst2, src2, E2, cur2, srcs2);

  // 6) layer 1 (fused linears + relu + binact)
  layer1_kernel<<<N1 / 4, 256, 0, stream>>>(rec1, offs1, srcs1,
                                            wbr1, m_r1, b_rel1, wbt1, m_t1, b_root1,
                                            bits2, alpha2);

  // 7) layer 2 (fused linears + log_softmax)
  layer2_kernel<<<N2 / 4, 256, 0, stream>>>(bits2, alpha2, offs2, srcs2,
                                            wbr2, m_r2, b_rel2, wbt2, m_t2, b_root2,
                                            (float*)d_out);
}